// Round 1
// baseline (478.025 us; speedup 1.0000x reference)
//
#include <hip/hip_runtime.h>
#include <hip/hip_bf16.h>

typedef float f32x4 __attribute__((ext_vector_type(4)));
typedef float fvec4 __attribute__((ext_vector_type(4)));
typedef __bf16 bf16x8 __attribute__((ext_vector_type(8)));

__device__ inline float fexp2(float x) {
#if __has_builtin(__builtin_amdgcn_exp2f)
    return __builtin_amdgcn_exp2f(x);
#else
    return exp2f(x);
#endif
}

#define MFMA_BF16(a, b, c) __builtin_amdgcn_mfma_f32_16x16x32_bf16((a), (b), (c), 0, 0, 0)

// ---------------- f32 -> bf16 elementwise convert (8 elems/thread) ----------------
__global__ __launch_bounds__(256) void cvt_kernel(const float* __restrict__ in,
                                                  __bf16* __restrict__ out, int n8) {
    int i = blockIdx.x * 256 + threadIdx.x;
    if (i >= n8) return;
    fvec4 a = ((const fvec4*)in)[2 * i];
    fvec4 b = ((const fvec4*)in)[2 * i + 1];
    bf16x8 o;
    o[0] = (__bf16)a[0]; o[1] = (__bf16)a[1]; o[2] = (__bf16)a[2]; o[3] = (__bf16)a[3];
    o[4] = (__bf16)b[0]; o[5] = (__bf16)b[1]; o[6] = (__bf16)b[2]; o[7] = (__bf16)b[3];
    ((bf16x8*)out)[i] = o;
}

// ---------------- W [K=768][N] f32  ->  Wt [N][768] bf16 (transpose+convert) -------
__global__ __launch_bounds__(256) void transpose_cvt_kernel(const float* __restrict__ src,
                                                            __bf16* __restrict__ dst, int N) {
    int n = blockIdx.x * 256 + threadIdx.x;
    int kg = blockIdx.y;  // 0..95 (k-groups of 8)
    if (n >= N) return;
    bf16x8 o;
#pragma unroll
    for (int j = 0; j < 8; j++) o[j] = (__bf16)src[(size_t)(kg * 8 + j) * N + n];
    *(bf16x8*)&dst[(size_t)n * 768 + kg * 8] = o;
}

// ---------------- bf16 MFMA GEMM: C[M,N] = A[M,768] * Bt[N,768]^T + bias -----------
// mode 0: scatter into Q/K/V bf16 [12][8192][64]; mode 1: f32 out [M][768]
__global__ __launch_bounds__(256, 2) void gemm_kernel(
    const __bf16* __restrict__ A, const __bf16* __restrict__ Bt,
    const float* __restrict__ bias,
    __bf16* __restrict__ Qo, __bf16* __restrict__ Ko, __bf16* __restrict__ Vo,
    float* __restrict__ Co, int mode) {
    __shared__ __bf16 Al[128][72];
    __shared__ __bf16 Bl[128][72];
    int tid = threadIdx.x;
    int wave = tid >> 6, lane = tid & 63;
    int quad = lane >> 4, l15 = lane & 15;
    int bm = blockIdx.x * 128, bn = blockIdx.y * 128;
    int wm = (wave >> 1) * 64, wn = (wave & 1) * 64;
    int lr = tid >> 3, lc = (tid & 7) * 8;
    f32x4 acc[4][4] = {};
    for (int k0 = 0; k0 < 768; k0 += 64) {
        __syncthreads();
#pragma unroll
        for (int i = 0; i < 4; i++) {
            int r = i * 32 + lr;
            *(bf16x8*)&Al[r][lc] = *(const bf16x8*)&A[(size_t)(bm + r) * 768 + k0 + lc];
            *(bf16x8*)&Bl[r][lc] = *(const bf16x8*)&Bt[(size_t)(bn + r) * 768 + k0 + lc];
        }
        __syncthreads();
#pragma unroll
        for (int ks = 0; ks < 2; ks++) {
            int ko = ks * 32 + quad * 8;
            bf16x8 af[4], bfr[4];
#pragma unroll
            for (int i = 0; i < 4; i++) af[i] = *(const bf16x8*)&Al[wm + i * 16 + l15][ko];
#pragma unroll
            for (int j = 0; j < 4; j++) bfr[j] = *(const bf16x8*)&Bl[wn + j * 16 + l15][ko];
#pragma unroll
            for (int i = 0; i < 4; i++)
#pragma unroll
                for (int j = 0; j < 4; j++)
                    acc[i][j] = MFMA_BF16(af[i], bfr[j], acc[i][j]);
        }
    }
#pragma unroll
    for (int j = 0; j < 4; j++) {
        int c = bn + wn + j * 16 + l15;
        float bv = bias[c];
        if (mode == 0) {
            int which = c / 768;
            int rem = c - which * 768;
            int h = rem >> 6, d = rem & 63;
            __bf16* dst = which == 0 ? Qo : (which == 1 ? Ko : Vo);
#pragma unroll
            for (int i = 0; i < 4; i++)
#pragma unroll
                for (int r = 0; r < 4; r++) {
                    int row = bm + wm + i * 16 + quad * 4 + r;
                    dst[((size_t)h * 8192 + row) * 64 + d] = (__bf16)(acc[i][j][r] + bv);
                }
        } else {
#pragma unroll
            for (int i = 0; i < 4; i++)
#pragma unroll
                for (int r = 0; r < 4; r++) {
                    int row = bm + wm + i * 16 + quad * 4 + r;
                    Co[(size_t)row * 768 + c] = acc[i][j][r] + bv;
                }
        }
    }
}

// ---------------- fused 3-segment flash attention --------------------------------
// grid: 12 heads * 128 tiles. Per head: t<32 -> seg0 (st=1,L=2048), t<96 -> seg1
// (st=2,L=4096), else seg2 (st=4,L=2048). Block = 4 waves, 64 q-rows (16/wave).
__global__ __launch_bounds__(256, 2) void attn_kernel(
    const __bf16* __restrict__ Qb, const __bf16* __restrict__ Kb,
    const __bf16* __restrict__ Vb, float* __restrict__ attnF) {
    __shared__ __bf16 Kl[64][72];       // [n][d]
    __shared__ __bf16 Vt[64][72];       // [d][swizzled n]
    __shared__ __bf16 Pl[4][16][72];    // per-wave P [m][n]
    int b = blockIdx.x;
    int head = b >> 7;
    int t = b & 127;
    int st, L, qt;
    if (t < 32)      { st = 1; L = 2048; qt = t; }
    else if (t < 96) { st = 2; L = 4096; qt = t - 32; }
    else             { st = 4; L = 2048; qt = t - 96; }
    int tid = threadIdx.x, wave = tid >> 6, lane = tid & 63;
    int quad = lane >> 4, l15 = lane & 15;
    const __bf16* Qh = Qb + (size_t)head * 8192 * 64;
    const __bf16* Kh = Kb + (size_t)head * 8192 * 64;
    const __bf16* Vh = Vb + (size_t)head * 8192 * 64;
    int qrow = qt * 64 + wave * 16 + l15;   // A-operand m = lane&15
    int qtok = qrow * st;
    bf16x8 qf0 = *(const bf16x8*)&Qh[(size_t)qtok * 64 + quad * 8];
    bf16x8 qf1 = *(const bf16x8*)&Qh[(size_t)qtok * 64 + 32 + quad * 8];
    f32x4 o[4] = {};
    float mrun[4] = {-1e30f, -1e30f, -1e30f, -1e30f};
    float lrun[4] = {0.f, 0.f, 0.f, 0.f};
    const float SC = 0.125f * 1.44269504089f;  // SCALE * log2(e)
    int lr = tid >> 3, lc8 = (tid & 7) * 8;
    int k8 = tid & 7;  // d-block this thread stages for V
    for (int nt = 0; nt < L / 64; nt++) {
        __syncthreads();
#pragma unroll
        for (int i = 0; i < 2; i++) {
            int n = i * 32 + lr;
            int tok = (nt * 64 + n) * st;
            *(bf16x8*)&Kl[n][lc8] = *(const bf16x8*)&Kh[(size_t)tok * 64 + lc8];
            bf16x8 vv = *(const bf16x8*)&Vh[(size_t)tok * 64 + lc8];
            int colb = (n & 7) + 8 * ((n >> 3) ^ k8);  // XOR swizzle: balanced banks
#pragma unroll
            for (int j = 0; j < 8; j++) Vt[lc8 + j][colb] = vv[j];
        }
        __syncthreads();
        // S = Q K^T : C-layout row = q (quad*4+r), col = kv (lane&15)
        f32x4 s[4];
#pragma unroll
        for (int ns = 0; ns < 4; ns++) {
            bf16x8 kf0 = *(const bf16x8*)&Kl[ns * 16 + l15][quad * 8];
            bf16x8 kf1 = *(const bf16x8*)&Kl[ns * 16 + l15][32 + quad * 8];
            f32x4 z = {};
            z = MFMA_BF16(qf0, kf0, z);
            s[ns] = MFMA_BF16(qf1, kf1, z);
        }
        // online softmax (raw scores; SCALE folded into exp2 argument)
        float al[4];
#pragma unroll
        for (int r = 0; r < 4; r++) {
            float tm = fmaxf(fmaxf(s[0][r], s[1][r]), fmaxf(s[2][r], s[3][r]));
            tm = fmaxf(tm, __shfl_xor(tm, 1, 64));
            tm = fmaxf(tm, __shfl_xor(tm, 2, 64));
            tm = fmaxf(tm, __shfl_xor(tm, 4, 64));
            tm = fmaxf(tm, __shfl_xor(tm, 8, 64));
            float mnew = fmaxf(mrun[r], tm);
            al[r] = fexp2((mrun[r] - mnew) * SC);
            mrun[r] = mnew;
            lrun[r] *= al[r];
        }
#pragma unroll
        for (int ds = 0; ds < 4; ds++) {
            o[ds][0] *= al[0]; o[ds][1] *= al[1];
            o[ds][2] *= al[2]; o[ds][3] *= al[3];
        }
#pragma unroll
        for (int ns = 0; ns < 4; ns++)
#pragma unroll
            for (int r = 0; r < 4; r++) {
                float p = fexp2((s[ns][r] - mrun[r]) * SC);
                lrun[r] += p;  // lane-local partial; cross-lane reduce at end
                Pl[wave][quad * 4 + r][ns * 16 + l15] = (__bf16)p;
            }
        __syncthreads();  // conservative: guarantee P transpose round-trip ordering
        bf16x8 pa0 = *(const bf16x8*)&Pl[wave][l15][quad * 8];
        bf16x8 pa1 = *(const bf16x8*)&Pl[wave][l15][32 + quad * 8];
#pragma unroll
        for (int ds = 0; ds < 4; ds++) {
            int dd = ds * 16 + l15;
            int db = dd >> 3;
            bf16x8 v0 = *(const bf16x8*)&Vt[dd][8 * (quad ^ db)];
            bf16x8 v1 = *(const bf16x8*)&Vt[dd][8 * ((4 + quad) ^ db)];
            o[ds] = MFMA_BF16(pa0, v0, o[ds]);
            o[ds] = MFMA_BF16(pa1, v1, o[ds]);
        }
    }
#pragma unroll
    for (int r = 0; r < 4; r++) {
        lrun[r] += __shfl_xor(lrun[r], 1, 64);
        lrun[r] += __shfl_xor(lrun[r], 2, 64);
        lrun[r] += __shfl_xor(lrun[r], 4, 64);
        lrun[r] += __shfl_xor(lrun[r], 8, 64);
        float inv = 1.0f / (3.0f * lrun[r]);  // 1/l * mean over 3 segments
        int row = qt * 64 + wave * 16 + quad * 4 + r;
        int tok = row * st;
#pragma unroll
        for (int ds = 0; ds < 4; ds++)
            atomicAdd(&attnF[(size_t)tok * 768 + head * 64 + ds * 16 + l15],
                      o[ds][r] * inv);
    }
}

extern "C" void kernel_launch(void* const* d_in, const int* in_sizes, int n_in,
                              void* d_out, int out_size, void* d_ws, size_t ws_size,
                              hipStream_t stream) {
    const float* x    = (const float*)d_in[0];
    const float* Wqkv = (const float*)d_in[1];
    const float* bqkv = (const float*)d_in[2];
    const float* Wout = (const float*)d_in[3];
    const float* bout = (const float*)d_in[4];
    float* out = (float*)d_out;
    (void)in_sizes; (void)n_in; (void)out_size; (void)ws_size;

    char* ws = (char*)d_ws;
    size_t off = 0;
    auto take = [&](size_t bytes) -> void* {
        void* p = ws + off;
        off += (bytes + 255) & ~(size_t)255;
        return p;
    };
    __bf16* xb    = (__bf16*)take((size_t)8192 * 768 * 2);   // also reused as attn bf16
    __bf16* WqkvT = (__bf16*)take((size_t)2304 * 768 * 2);
    __bf16* WoutT = (__bf16*)take((size_t)768 * 768 * 2);
    __bf16* Qb    = (__bf16*)take((size_t)12 * 8192 * 64 * 2);
    __bf16* Kb    = (__bf16*)take((size_t)12 * 8192 * 64 * 2);
    __bf16* Vb    = (__bf16*)take((size_t)12 * 8192 * 64 * 2);
    float*  attnF = (float*)take((size_t)8192 * 768 * 4);

    hipMemsetAsync(attnF, 0, (size_t)8192 * 768 * 4, stream);
    cvt_kernel<<<3072, 256, 0, stream>>>(x, xb, 8192 * 768 / 8);
    transpose_cvt_kernel<<<dim3(9, 96), 256, 0, stream>>>(Wqkv, WqkvT, 2304);
    transpose_cvt_kernel<<<dim3(3, 96), 256, 0, stream>>>(Wout, WoutT, 768);
    gemm_kernel<<<dim3(64, 18), 256, 0, stream>>>(xb, WqkvT, bqkv, Qb, Kb, Vb, nullptr, 0);
    attn_kernel<<<1536, 256, 0, stream>>>(Qb, Kb, Vb, attnF);
    cvt_kernel<<<3072, 256, 0, stream>>>(attnF, xb, 8192 * 768 / 8);
    gemm_kernel<<<dim3(64, 6), 256, 0, stream>>>(xb, WoutT, bout, nullptr, nullptr, nullptr,
                                                 out, 1);
}

// Round 2
// 380.529 us; speedup vs baseline: 1.2562x; 1.2562x over previous
//
#include <hip/hip_runtime.h>
#include <hip/hip_bf16.h>

typedef float f32x4 __attribute__((ext_vector_type(4)));
typedef float fvec4 __attribute__((ext_vector_type(4)));
typedef __bf16 bf16x8 __attribute__((ext_vector_type(8)));
typedef __bf16 bf16x4 __attribute__((ext_vector_type(4)));

__device__ inline float fexp2(float x) {
#if __has_builtin(__builtin_amdgcn_exp2f)
    return __builtin_amdgcn_exp2f(x);
#else
    return exp2f(x);
#endif
}

#define MFMA_BF16(a, b, c) __builtin_amdgcn_mfma_f32_16x16x32_bf16((a), (b), (c), 0, 0, 0)

// async 16B global -> LDS DMA (lane i lands at ldsbase + i*16; lds ptr wave-uniform)
__device__ __forceinline__ void gl2lds16(const void* g, void* l) {
    __builtin_amdgcn_global_load_lds((const __attribute__((address_space(1))) void*)g,
                                     (__attribute__((address_space(3))) void*)l, 16, 0, 0);
}

// ---------------- W [K=768][N] f32  ->  Wt [N][768] bf16 (transpose+convert) -------
__global__ __launch_bounds__(256) void transpose_cvt_kernel(const float* __restrict__ src,
                                                            __bf16* __restrict__ dst, int N) {
    int n = blockIdx.x * 256 + threadIdx.x;
    int kg = blockIdx.y;  // 0..95 (k-groups of 8)
    if (n >= N) return;
    bf16x8 o;
#pragma unroll
    for (int j = 0; j < 8; j++) o[j] = (__bf16)src[(size_t)(kg * 8 + j) * N + n];
    *(bf16x8*)&dst[(size_t)n * 768 + kg * 8] = o;
}

// ------- V [12][8192][64] -> compacted V^T per segment: [12][64][Lc], 16B-chunk ----
// chunk index in output is NOT swizzled (plain [d][ct]); LDS swizzle is internal.
__global__ __launch_bounds__(256) void vtrans_kernel(const __bf16* __restrict__ Vb,
                                                     __bf16* __restrict__ Vt0,
                                                     __bf16* __restrict__ Vt1,
                                                     __bf16* __restrict__ Vt2) {
    __shared__ __bf16 T[64 * 64];
    int bid = blockIdx.x;
    int st, Lc, head, t;
    __bf16* dst;
    if (bid < 768)       { int i = bid;        st = 2; Lc = 4096; head = i >> 6; t = i & 63; dst = Vt1; }
    else if (bid < 1152) { int i = bid - 768;  st = 1; Lc = 2048; head = i >> 5; t = i & 31; dst = Vt0; }
    else                 { int i = bid - 1152; st = 4; Lc = 2048; head = i >> 5; t = i & 31; dst = Vt2; }
    int tid = threadIdx.x;
    const __bf16* src = Vb + (size_t)head * 8192 * 64;
    int d8 = (tid & 7) * 8, swz = tid & 7;
#pragma unroll
    for (int it = 0; it < 2; it++) {
        int ct = (tid >> 3) + it * 32;
        bf16x8 vv = *(const bf16x8*)&src[(size_t)((t * 64 + ct) * st) * 64 + d8];
#pragma unroll
        for (int j = 0; j < 8; j++)
            T[(d8 + j) * 64 + (((ct >> 3) ^ swz) * 8 + (ct & 7))] = vv[j];
    }
    __syncthreads();
    __bf16* dh = dst + (size_t)head * 64 * Lc;
#pragma unroll
    for (int it = 0; it < 2; it++) {
        int s = tid + it * 256;
        int d = s >> 3, cbp = s & 7;
        int cb = cbp ^ ((d >> 3) & 7);
        *(bf16x8*)&dh[(size_t)d * Lc + t * 64 + cb * 8] = *(const bf16x8*)&T[s * 8];
    }
}

// ---------------- bf16 MFMA GEMM: C[M,N] = A_f32[M,768] * Bt[N,768]^T + bias -------
// A is f32 (converted to bf16 at LDS-store time). mode 0: scatter Q/K/V; mode 1: f32 C.
__global__ __launch_bounds__(256, 2) void gemm_kernel(
    const float* __restrict__ Af, const __bf16* __restrict__ Bt,
    const float* __restrict__ bias,
    __bf16* __restrict__ Qo, __bf16* __restrict__ Ko, __bf16* __restrict__ Vo,
    float* __restrict__ Co, int mode) {
    __shared__ __bf16 Al[128][72];
    __shared__ __bf16 Bl[128][72];
    int tid = threadIdx.x;
    int wave = tid >> 6, lane = tid & 63;
    int quad = lane >> 4, l15 = lane & 15;
    int bm = blockIdx.x * 128, bn = blockIdx.y * 128;
    int wm = (wave >> 1) * 64, wn = (wave & 1) * 64;
    int lr = tid >> 3, lc = (tid & 7) * 8;
    f32x4 acc[4][4] = {};
    for (int k0 = 0; k0 < 768; k0 += 64) {
        __syncthreads();
#pragma unroll
        for (int i = 0; i < 4; i++) {
            int r = i * 32 + lr;
            const float* ap = &Af[(size_t)(bm + r) * 768 + k0 + lc];
            fvec4 a0 = *(const fvec4*)ap;
            fvec4 a1 = *(const fvec4*)(ap + 4);
            bf16x8 av;
            av[0] = (__bf16)a0[0]; av[1] = (__bf16)a0[1]; av[2] = (__bf16)a0[2]; av[3] = (__bf16)a0[3];
            av[4] = (__bf16)a1[0]; av[5] = (__bf16)a1[1]; av[6] = (__bf16)a1[2]; av[7] = (__bf16)a1[3];
            *(bf16x8*)&Al[r][lc] = av;
            *(bf16x8*)&Bl[r][lc] = *(const bf16x8*)&Bt[(size_t)(bn + r) * 768 + k0 + lc];
        }
        __syncthreads();
#pragma unroll
        for (int ks = 0; ks < 2; ks++) {
            int ko = ks * 32 + quad * 8;
            bf16x8 af[4], bfr[4];
#pragma unroll
            for (int i = 0; i < 4; i++) af[i] = *(const bf16x8*)&Al[wm + i * 16 + l15][ko];
#pragma unroll
            for (int j = 0; j < 4; j++) bfr[j] = *(const bf16x8*)&Bl[wn + j * 16 + l15][ko];
#pragma unroll
            for (int i = 0; i < 4; i++)
#pragma unroll
                for (int j = 0; j < 4; j++)
                    acc[i][j] = MFMA_BF16(af[i], bfr[j], acc[i][j]);
        }
    }
#pragma unroll
    for (int j = 0; j < 4; j++) {
        int c = bn + wn + j * 16 + l15;
        float bv = bias[c];
        if (mode == 0) {
            int which = c / 768;
            int rem = c - which * 768;
            int h = rem >> 6, d = rem & 63;
            __bf16* dst = which == 0 ? Qo : (which == 1 ? Ko : Vo);
#pragma unroll
            for (int i = 0; i < 4; i++)
#pragma unroll
                for (int r = 0; r < 4; r++) {
                    int row = bm + wm + i * 16 + quad * 4 + r;
                    dst[((size_t)h * 8192 + row) * 64 + d] = (__bf16)(acc[i][j][r] + bv);
                }
        } else {
#pragma unroll
            for (int i = 0; i < 4; i++)
#pragma unroll
                for (int r = 0; r < 4; r++) {
                    int row = bm + wm + i * 16 + quad * 4 + r;
                    Co[(size_t)row * 768 + c] = acc[i][j][r] + bv;
                }
        }
    }
}

// ---------------- fused 3-segment flash attention, S^T formulation ----------------
// St = K·Q^T (rows=kv, cols=q on lane&15). P stays in registers (C-layout == B-op
// layout for kv-as-K). PV packs two 16-kv chunks into one 16x16x32 MFMA.
// Block: 4 waves, 128 q (32 q / wave as 2 q-groups). K/V staged by global_load_lds DMA.
__global__ __launch_bounds__(256, 2) void attn_kernel(
    const __bf16* __restrict__ Qb, const __bf16* __restrict__ Kb,
    const __bf16* __restrict__ Vt0, const __bf16* __restrict__ Vt1,
    const __bf16* __restrict__ Vt2, float* __restrict__ attnF) {
    __shared__ __bf16 Kl[64 * 64];  // [kv][16B-block swizzled d]
    __shared__ __bf16 Vl[64 * 64];  // [d][16B-block swizzled kv]
    int bid = blockIdx.x;
    int st, L, head, qt;
    const __bf16* Vts;
    if (bid < 384)      { st = 2; L = 4096; head = bid >> 5; qt = bid & 31; Vts = Vt1; }
    else if (bid < 576) { int i = bid - 384; st = 1; L = 2048; head = i >> 4; qt = i & 15; Vts = Vt0; }
    else                { int i = bid - 576; st = 4; L = 2048; head = i >> 4; qt = i & 15; Vts = Vt2; }
    int tid = threadIdx.x, wave = tid >> 6, lane = tid & 63;
    int quad = lane >> 4, l15 = lane & 15;
    const __bf16* Qh = Qb + (size_t)head * 8192 * 64;
    const __bf16* Kh = Kb + (size_t)head * 8192 * 64;
    const __bf16* Vh = Vts + (size_t)head * 64 * L;  // compacted [64][L]
    // Q as B-operand, kept in registers: q = qt*128 + wave*32 + qg*16 + l15
    bf16x8 qf[2][2];
#pragma unroll
    for (int qg = 0; qg < 2; qg++) {
        size_t qtok = (size_t)((qt * 128 + wave * 32 + qg * 16 + l15) * st);
        qf[qg][0] = *(const bf16x8*)&Qh[qtok * 64 + quad * 8];
        qf[qg][1] = *(const bf16x8*)&Qh[qtok * 64 + 32 + quad * 8];
    }
    f32x4 o[2][4] = {};
    float mrun[2] = {-1e30f, -1e30f}, lrun[2] = {0.f, 0.f};
    const float SC = 0.125f * 1.44269504089f;  // SCALE * log2(e)
    // DMA slot decode (slot s: 16B to LDS offset s*16)
    int s0 = tid, s1 = tid + 256;
    int kv0 = s0 >> 3, kdb0 = (s0 & 7) ^ (kv0 & 7);
    int kv1 = s1 >> 3, kdb1 = (s1 & 7) ^ (kv1 & 7);
    int vd0 = kv0, vcb0 = (s0 & 7) ^ (vd0 & 7);
    int vd1 = kv1, vcb1 = (s1 & 7) ^ (vd1 & 7);
    char* KlB = (char*)Kl;
    char* VlB = (char*)Vl;
    int swzk = l15 & 7;
    for (int nt = 0; nt < L / 64; nt++) {
        int t0 = nt * 64;
        __syncthreads();
        gl2lds16(&Kh[(size_t)((t0 + kv0) * st) * 64 + kdb0 * 8], KlB + wave * 1024);
        gl2lds16(&Kh[(size_t)((t0 + kv1) * st) * 64 + kdb1 * 8], KlB + 4096 + wave * 1024);
        gl2lds16(&Vh[(size_t)vd0 * L + t0 + vcb0 * 8], VlB + wave * 1024);
        gl2lds16(&Vh[(size_t)vd1 * L + t0 + vcb1 * 8], VlB + 4096 + wave * 1024);
        __syncthreads();
        // St = K Q^T : rows kv = quad*4+r (per 16-chunk), cols q = l15
        f32x4 sarr[4][2];
#pragma unroll
        for (int c = 0; c < 4; c++) {
            int krow = (c * 16 + l15) * 64;
            bf16x8 kf0 = *(const bf16x8*)&Kl[krow + ((quad ^ swzk) * 8)];
            bf16x8 kf1 = *(const bf16x8*)&Kl[krow + (((4 + quad) ^ swzk) * 8)];
#pragma unroll
            for (int qg = 0; qg < 2; qg++) {
                f32x4 z = {};
                z = MFMA_BF16(kf0, qf[qg][0], z);
                sarr[c][qg] = MFMA_BF16(kf1, qf[qg][1], z);
            }
        }
        // online softmax over kv (in-lane over 16 vals, cross-quad via 2 shfls)
        bf16x8 pf8[2][2];
#pragma unroll
        for (int qg = 0; qg < 2; qg++) {
            float mx = fmaxf(fmaxf(fmaxf(sarr[0][qg][0], sarr[0][qg][1]),
                                   fmaxf(sarr[0][qg][2], sarr[0][qg][3])),
                             fmaxf(fmaxf(sarr[1][qg][0], sarr[1][qg][1]),
                                   fmaxf(sarr[1][qg][2], sarr[1][qg][3])));
            mx = fmaxf(mx, fmaxf(fmaxf(fmaxf(sarr[2][qg][0], sarr[2][qg][1]),
                                       fmaxf(sarr[2][qg][2], sarr[2][qg][3])),
                                 fmaxf(fmaxf(sarr[3][qg][0], sarr[3][qg][1]),
                                       fmaxf(sarr[3][qg][2], sarr[3][qg][3]))));
            mx = fmaxf(mx, __shfl_xor(mx, 16, 64));
            mx = fmaxf(mx, __shfl_xor(mx, 32, 64));
            float mnew = fmaxf(mrun[qg], mx);
            float al = fexp2((mrun[qg] - mnew) * SC);
            mrun[qg] = mnew;
            lrun[qg] *= al;
#pragma unroll
            for (int ds = 0; ds < 4; ds++) {
                o[qg][ds][0] *= al; o[qg][ds][1] *= al;
                o[qg][ds][2] *= al; o[qg][ds][3] *= al;
            }
#pragma unroll
            for (int c = 0; c < 4; c++)
#pragma unroll
                for (int r = 0; r < 4; r++) {
                    float p = fexp2((sarr[c][qg][r] - mnew) * SC);
                    lrun[qg] += p;
                    pf8[qg][c >> 1][(c & 1) * 4 + r] = (__bf16)p;
                }
        }
        // O^T += V^T P : superchunk u packs chunks {2u, 2u+1} as k j<4 / j>=4
#pragma unroll
        for (int u = 0; u < 2; u++) {
#pragma unroll
            for (int ds = 0; ds < 4; ds++) {
                int d = ds * 16 + l15;
                int base = d * 64 + (quad & 1) * 4;
                int swz = d & 7;
                bf16x4 va = *(const bf16x4*)&Vl[base + (((u * 4 + (quad >> 1)) ^ swz) * 8)];
                bf16x4 vb = *(const bf16x4*)&Vl[base + (((u * 4 + 2 + (quad >> 1)) ^ swz) * 8)];
                bf16x8 vf;
                vf[0] = va[0]; vf[1] = va[1]; vf[2] = va[2]; vf[3] = va[3];
                vf[4] = vb[0]; vf[5] = vb[1]; vf[6] = vb[2]; vf[7] = vb[3];
                o[0][ds] = MFMA_BF16(vf, pf8[0][u], o[0][ds]);
                o[1][ds] = MFMA_BF16(vf, pf8[1][u], o[1][ds]);
            }
        }
    }
    // epilogue: normalize (1/l * 1/3) and atomically accumulate the segment mean
#pragma unroll
    for (int qg = 0; qg < 2; qg++) {
        float l = lrun[qg];
        l += __shfl_xor(l, 16, 64);
        l += __shfl_xor(l, 32, 64);
        float inv = 1.0f / (3.0f * l);
        int q = qt * 128 + wave * 32 + qg * 16 + l15;
        float* dst = &attnF[(size_t)(q * st) * 768 + head * 64];
#pragma unroll
        for (int ds = 0; ds < 4; ds++)
#pragma unroll
            for (int r = 0; r < 4; r++)
                atomicAdd(&dst[ds * 16 + quad * 4 + r], o[qg][ds][r] * inv);
    }
}

extern "C" void kernel_launch(void* const* d_in, const int* in_sizes, int n_in,
                              void* d_out, int out_size, void* d_ws, size_t ws_size,
                              hipStream_t stream) {
    const float* x    = (const float*)d_in[0];
    const float* Wqkv = (const float*)d_in[1];
    const float* bqkv = (const float*)d_in[2];
    const float* Wout = (const float*)d_in[3];
    const float* bout = (const float*)d_in[4];
    float* out = (float*)d_out;
    (void)in_sizes; (void)n_in; (void)out_size; (void)ws_size;

    char* ws = (char*)d_ws;
    size_t off = 0;
    auto take = [&](size_t bytes) -> void* {
        void* p = ws + off;
        off += (bytes + 255) & ~(size_t)255;
        return p;
    };
    __bf16* WqkvT = (__bf16*)take((size_t)2304 * 768 * 2);
    __bf16* WoutT = (__bf16*)take((size_t)768 * 768 * 2);
    __bf16* Qb    = (__bf16*)take((size_t)12 * 8192 * 64 * 2);
    __bf16* Kb    = (__bf16*)take((size_t)12 * 8192 * 64 * 2);
    __bf16* Vb    = (__bf16*)take((size_t)12 * 8192 * 64 * 2);
    float*  attnF = (float*)take((size_t)8192 * 768 * 4);
    __bf16* Vt0   = (__bf16*)take((size_t)12 * 64 * 2048 * 2);
    __bf16* Vt1   = (__bf16*)take((size_t)12 * 64 * 4096 * 2);
    __bf16* Vt2   = (__bf16*)take((size_t)12 * 64 * 2048 * 2);

    hipMemsetAsync(attnF, 0, (size_t)8192 * 768 * 4, stream);
    transpose_cvt_kernel<<<dim3(9, 96), 256, 0, stream>>>(Wqkv, WqkvT, 2304);
    transpose_cvt_kernel<<<dim3(3, 96), 256, 0, stream>>>(Wout, WoutT, 768);
    gemm_kernel<<<dim3(64, 18), 256, 0, stream>>>(x, WqkvT, bqkv, Qb, Kb, Vb, nullptr, 0);
    vtrans_kernel<<<1536, 256, 0, stream>>>(Vb, Vt0, Vt1, Vt2);
    attn_kernel<<<768, 256, 0, stream>>>(Qb, Kb, Vt0, Vt1, Vt2, attnF);
    gemm_kernel<<<dim3(64, 6), 256, 0, stream>>>(attnF, WoutT, bout, nullptr, nullptr,
                                                 nullptr, out, 1);
}

// Round 3
// 318.583 us; speedup vs baseline: 1.5005x; 1.1944x over previous
//
#include <hip/hip_runtime.h>
#include <hip/hip_bf16.h>

typedef float f32x4 __attribute__((ext_vector_type(4)));
typedef float fvec4 __attribute__((ext_vector_type(4)));
typedef __bf16 bf16x8 __attribute__((ext_vector_type(8)));

__device__ inline float fexp2(float x) {
#if __has_builtin(__builtin_amdgcn_exp2f)
    return __builtin_amdgcn_exp2f(x);
#else
    return exp2f(x);
#endif
}

#define MFMA_BF16(a, b, c) __builtin_amdgcn_mfma_f32_16x16x32_bf16((a), (b), (c), 0, 0, 0)

__device__ __forceinline__ void gl2lds16(const void* g, void* l) {
    __builtin_amdgcn_global_load_lds((const __attribute__((address_space(1))) void*)g,
                                     (__attribute__((address_space(3))) void*)l, 16, 0, 0);
}

// seg offsets (elements) inside compact Q/K/V buffers: [seg0 12x2048][seg1 12x4096][seg2 12x2048] x64d
#define SEG1OFF ((size_t)12 * 2048 * 64)
#define SEG2OFF ((size_t)12 * 6144 * 64)
#define QSCALE 0.18033688f  // SCALE * log2(e)

// ---------------- W [K=768][N] f32 -> Wt [N][768] bf16 ----------------------------
__global__ __launch_bounds__(256) void transpose_cvt_kernel(const float* __restrict__ src,
                                                            __bf16* __restrict__ dst, int N) {
    int n = blockIdx.x * 256 + threadIdx.x;
    int kg = blockIdx.y;
    if (n >= N) return;
    bf16x8 o;
#pragma unroll
    for (int j = 0; j < 8; j++) o[j] = (__bf16)src[(size_t)(kg * 8 + j) * N + n];
    *(bf16x8*)&dst[(size_t)n * 768 + kg * 8] = o;
}

// ---- Vc compact [seg][head][pos][64] -> Vt [seg][head][64][Lc] in MFMA-k order ----
// position t*64+k holds token t*64+kv(k), kv(k) = u*32 + quad*4 + (j&3) + (j>>2)*16
__global__ __launch_bounds__(256) void vtrans_kernel(const __bf16* __restrict__ Vc,
                                                     __bf16* __restrict__ Vt) {
    __shared__ __bf16 T[64][68];
    int bid = blockIdx.x;
    int Lc, head, t;
    size_t soff;
    if (bid < 768)       { Lc = 4096; head = bid >> 6; t = bid & 63; soff = SEG1OFF; }
    else if (bid < 1152) { int i = bid - 768; Lc = 2048; head = i >> 5; t = i & 31; soff = 0; }
    else                 { int i = bid - 1152; Lc = 2048; head = i >> 5; t = i & 31; soff = SEG2OFF; }
    const __bf16* src = Vc + soff + (size_t)head * Lc * 64;
    __bf16* dst = Vt + soff + (size_t)head * 64 * Lc;
    int tid = threadIdx.x;
#pragma unroll
    for (int it = 0; it < 2; it++) {
        int s = tid + it * 256;
        int kvr = s >> 3, d8 = (s & 7) * 8;
        bf16x8 vv = *(const bf16x8*)&src[(size_t)(t * 64 + kvr) * 64 + d8];
#pragma unroll
        for (int j = 0; j < 8; j++) T[d8 + j][kvr] = vv[j];
    }
    __syncthreads();
#pragma unroll
    for (int it = 0; it < 2; it++) {
        int s = tid + it * 256;
        int d = s >> 3, ck = s & 7;
        int kb = (ck >> 2) * 32 + (ck & 3) * 4;
        bf16x8 o;
#pragma unroll
        for (int J = 0; J < 8; J++) o[J] = T[d][kb + (J & 3) + (J >> 2) * 16];
        *(bf16x8*)&dst[(size_t)d * Lc + t * 64 + ck * 8] = o;
    }
}

// ---------------- bf16 MFMA GEMM ---------------------------------------------------
// mode 0: A=f32 x, writes compact Qc(scaled)/Kc/Vc per covering segment.
// mode 1: A=bf16 attnF, writes f32 Co + bias.
__global__ __launch_bounds__(256, 2) void gemm_kernel(
    const float* __restrict__ Af, const __bf16* __restrict__ Ab,
    const __bf16* __restrict__ Bt, const float* __restrict__ bias,
    __bf16* __restrict__ Qc, __bf16* __restrict__ Kc, __bf16* __restrict__ Vc,
    float* __restrict__ Co, int mode) {
    __shared__ __bf16 Al[128][72];
    __shared__ __bf16 Bl[128][72];
    int tid = threadIdx.x;
    int wave = tid >> 6, lane = tid & 63;
    int quad = lane >> 4, l15 = lane & 15;
    int bm = blockIdx.x * 128, bn = blockIdx.y * 128;
    int wm = (wave >> 1) * 64, wn = (wave & 1) * 64;
    int lr = tid >> 3, lc = (tid & 7) * 8;
    f32x4 acc[4][4] = {};
    for (int k0 = 0; k0 < 768; k0 += 64) {
        __syncthreads();
#pragma unroll
        for (int i = 0; i < 4; i++) {
            int r = i * 32 + lr;
            if (mode == 0) {
                const float* ap = &Af[(size_t)(bm + r) * 768 + k0 + lc];
                fvec4 a0 = *(const fvec4*)ap;
                fvec4 a1 = *(const fvec4*)(ap + 4);
                bf16x8 av;
                av[0] = (__bf16)a0[0]; av[1] = (__bf16)a0[1]; av[2] = (__bf16)a0[2]; av[3] = (__bf16)a0[3];
                av[4] = (__bf16)a1[0]; av[5] = (__bf16)a1[1]; av[6] = (__bf16)a1[2]; av[7] = (__bf16)a1[3];
                *(bf16x8*)&Al[r][lc] = av;
            } else {
                *(bf16x8*)&Al[r][lc] = *(const bf16x8*)&Ab[(size_t)(bm + r) * 768 + k0 + lc];
            }
            *(bf16x8*)&Bl[r][lc] = *(const bf16x8*)&Bt[(size_t)(bn + r) * 768 + k0 + lc];
        }
        __syncthreads();
#pragma unroll
        for (int ks = 0; ks < 2; ks++) {
            int ko = ks * 32 + quad * 8;
            bf16x8 af[4], bfr[4];
#pragma unroll
            for (int i = 0; i < 4; i++) af[i] = *(const bf16x8*)&Al[wm + i * 16 + l15][ko];
#pragma unroll
            for (int j = 0; j < 4; j++) bfr[j] = *(const bf16x8*)&Bl[wn + j * 16 + l15][ko];
#pragma unroll
            for (int i = 0; i < 4; i++)
#pragma unroll
                for (int j = 0; j < 4; j++)
                    acc[i][j] = MFMA_BF16(af[i], bfr[j], acc[i][j]);
        }
    }
#pragma unroll
    for (int j = 0; j < 4; j++) {
        int c = bn + wn + j * 16 + l15;
        float bv = bias[c];
        if (mode == 0) {
            int which = c / 768;
            int rem = c - which * 768;
            int h = rem >> 6, d = rem & 63;
            __bf16* dst = which == 0 ? Qc : (which == 1 ? Kc : Vc);
            float scl = which == 0 ? QSCALE : 1.0f;
            __bf16* p0 = dst + (size_t)h * 2048 * 64 + d;
            __bf16* p1 = dst + SEG1OFF + (size_t)h * 4096 * 64 + d;
            __bf16* p2 = dst + SEG2OFF + (size_t)h * 2048 * 64 + d;
#pragma unroll
            for (int i = 0; i < 4; i++)
#pragma unroll
                for (int r = 0; r < 4; r++) {
                    int row = bm + wm + i * 16 + quad * 4 + r;
                    __bf16 v = (__bf16)((acc[i][j][r] + bv) * scl);
                    if (row < 2048)   p0[(size_t)row * 64] = v;
                    if (!(row & 1))   p1[(size_t)(row >> 1) * 64] = v;
                    if (!(row & 3))   p2[(size_t)(row >> 2) * 64] = v;
                }
        } else {
#pragma unroll
            for (int i = 0; i < 4; i++)
#pragma unroll
                for (int r = 0; r < 4; r++) {
                    int row = bm + wm + i * 16 + quad * 4 + r;
                    Co[(size_t)row * 768 + c] = acc[i][j][r] + bv;
                }
        }
    }
}

// ---------------- fused flash attention, S^T form, no-max softmax, kv-split --------
// 1152 uniform blocks x 32 iters. Unnormalized O + l to private buffers (no atomics).
__global__ __launch_bounds__(256, 2) void attn_kernel(
    const __bf16* __restrict__ Qcb, const __bf16* __restrict__ Kcb,
    const __bf16* __restrict__ Vtb,
    float* __restrict__ O0, float* __restrict__ O1a, float* __restrict__ O1b,
    float* __restrict__ O2, float* __restrict__ L0, float* __restrict__ L1a,
    float* __restrict__ L1b, float* __restrict__ L2) {
    __shared__ __bf16 Kl[64 * 64];
    __shared__ __bf16 Vl[64 * 64];
    int bid = blockIdx.x;
    int seg, half = 0, head, qt, Lc;
    if (bid < 768)      { int i = bid >> 1; half = bid & 1; head = i >> 5; qt = i & 31; Lc = 4096; seg = 1; }
    else if (bid < 960) { int i = bid - 768; head = i >> 4; qt = i & 15; Lc = 2048; seg = 0; }
    else                { int i = bid - 960; head = i >> 4; qt = i & 15; Lc = 2048; seg = 2; }
    size_t soff = seg == 0 ? 0 : (seg == 1 ? SEG1OFF : SEG2OFF);
    const __bf16* Qh = Qcb + soff + (size_t)head * Lc * 64;
    const __bf16* Kh = Kcb + soff + (size_t)head * Lc * 64;
    const __bf16* Vh = Vtb + soff + (size_t)head * 64 * Lc;
    float* Ob;
    float* Lb;
    if (seg == 0)      { Ob = O0; Lb = L0 + head * 2048; }
    else if (seg == 1) { Ob = half ? O1b : O1a; Lb = (half ? L1b : L1a) + head * 4096; }
    else               { Ob = O2; Lb = L2 + head * 2048; }
    int kvb = (seg == 1) ? half * 32 : 0;
    int tid = threadIdx.x, wave = tid >> 6, lane = tid & 63;
    int quad = lane >> 4, l15 = lane & 15;
    bf16x8 qf[2][2];
#pragma unroll
    for (int qg = 0; qg < 2; qg++) {
        size_t qpos = (size_t)(qt * 128 + wave * 32 + qg * 16 + l15);
        qf[qg][0] = *(const bf16x8*)&Qh[qpos * 64 + quad * 8];
        qf[qg][1] = *(const bf16x8*)&Qh[qpos * 64 + 32 + quad * 8];
    }
    f32x4 o[2][4] = {};
    float lrun[2] = {0.f, 0.f};
    // DMA slot decode
    int kv0 = tid >> 3, cl0 = tid & 7;
    int kdb0 = cl0 ^ (kv0 & 7);
    int kv1 = kv0 + 32, kdb1 = cl0 ^ (kv1 & 7);
    char* KlB = (char*)Kl;
    char* VlB = (char*)Vl;
    int swz = l15 & 7;
    for (int nt = 0; nt < 32; nt++) {
        int t0 = (kvb + nt) * 64;
        __syncthreads();
        gl2lds16(&Kh[(size_t)(t0 + kv0) * 64 + kdb0 * 8], KlB + wave * 1024);
        gl2lds16(&Kh[(size_t)(t0 + kv1) * 64 + kdb1 * 8], KlB + 4096 + wave * 1024);
        gl2lds16(&Vh[(size_t)kv0 * Lc + t0 + kdb0 * 8], VlB + wave * 1024);
        gl2lds16(&Vh[(size_t)kv1 * Lc + t0 + kdb1 * 8], VlB + 4096 + wave * 1024);
        __syncthreads();
        f32x4 sarr[4][2];
#pragma unroll
        for (int c = 0; c < 4; c++) {
            int krow = (c * 16 + l15) * 64;
            bf16x8 kf0 = *(const bf16x8*)&Kl[krow + ((quad ^ swz) * 8)];
            bf16x8 kf1 = *(const bf16x8*)&Kl[krow + (((4 + quad) ^ swz) * 8)];
#pragma unroll
            for (int qg = 0; qg < 2; qg++) {
                f32x4 z = {};
                z = MFMA_BF16(kf0, qf[qg][0], z);
                sarr[c][qg] = MFMA_BF16(kf1, qf[qg][1], z);
            }
        }
        bf16x8 pf8[2][2];
#pragma unroll
        for (int qg = 0; qg < 2; qg++)
#pragma unroll
            for (int c = 0; c < 4; c++)
#pragma unroll
                for (int r = 0; r < 4; r++) {
                    float p = fexp2(sarr[c][qg][r]);
                    lrun[qg] += p;
                    pf8[qg][c >> 1][(c & 1) * 4 + r] = (__bf16)p;
                }
#pragma unroll
        for (int u = 0; u < 2; u++)
#pragma unroll
            for (int ds = 0; ds < 4; ds++) {
                int d = ds * 16 + l15;
                bf16x8 vf = *(const bf16x8*)&Vl[d * 64 + (((u * 4 + quad) ^ swz) * 8)];
                o[0][ds] = MFMA_BF16(vf, pf8[0][u], o[0][ds]);
                o[1][ds] = MFMA_BF16(vf, pf8[1][u], o[1][ds]);
            }
    }
#pragma unroll
    for (int qg = 0; qg < 2; qg++) {
        float l = lrun[qg];
        l += __shfl_xor(l, 16, 64);
        l += __shfl_xor(l, 32, 64);
        int pos = qt * 128 + wave * 32 + qg * 16 + l15;
        float* orow = Ob + (size_t)pos * 768 + head * 64;
#pragma unroll
        for (int ds = 0; ds < 4; ds++)
            *(f32x4*)&orow[ds * 16 + quad * 4] = o[qg][ds];
        if (lane < 16) Lb[qt * 128 + wave * 32 + qg * 16 + lane] = l;
    }
}

// ---------------- combine: attnF[q][768] = (1/3) * sum_seg O_seg/l_seg, bf16 -------
__global__ __launch_bounds__(256) void combine_kernel(
    const float* __restrict__ O0, const float* __restrict__ O1a,
    const float* __restrict__ O1b, const float* __restrict__ O2,
    const float* __restrict__ L0, const float* __restrict__ L1a,
    const float* __restrict__ L1b, const float* __restrict__ L2,
    __bf16* __restrict__ attnF) {
    int g = blockIdx.x * 256 + threadIdx.x;  // 8192*96
    int q = g / 96;
    int cs = (g - q * 96) * 8;
    int head = cs >> 6;
    f32x4 a0 = {}, a1 = {};
    if (q < 2048) {
        float inv = 1.0f / L0[head * 2048 + q];
        const f32x4* p = (const f32x4*)&O0[(size_t)q * 768 + cs];
        a0 += p[0] * inv; a1 += p[1] * inv;
    }
    if (!(q & 1)) {
        int p1 = q >> 1;
        float inv = 1.0f / (L1a[head * 4096 + p1] + L1b[head * 4096 + p1]);
        const f32x4* pa = (const f32x4*)&O1a[(size_t)p1 * 768 + cs];
        const f32x4* pb = (const f32x4*)&O1b[(size_t)p1 * 768 + cs];
        a0 += (pa[0] + pb[0]) * inv; a1 += (pa[1] + pb[1]) * inv;
    }
    if (!(q & 3)) {
        int p2 = q >> 2;
        float inv = 1.0f / L2[head * 2048 + p2];
        const f32x4* p = (const f32x4*)&O2[(size_t)p2 * 768 + cs];
        a0 += p[0] * inv; a1 += p[1] * inv;
    }
    const float third = 1.0f / 3.0f;
    bf16x8 ov;
    ov[0] = (__bf16)(a0[0] * third); ov[1] = (__bf16)(a0[1] * third);
    ov[2] = (__bf16)(a0[2] * third); ov[3] = (__bf16)(a0[3] * third);
    ov[4] = (__bf16)(a1[0] * third); ov[5] = (__bf16)(a1[1] * third);
    ov[6] = (__bf16)(a1[2] * third); ov[7] = (__bf16)(a1[3] * third);
    *(bf16x8*)&attnF[(size_t)q * 768 + cs] = ov;
}

extern "C" void kernel_launch(void* const* d_in, const int* in_sizes, int n_in,
                              void* d_out, int out_size, void* d_ws, size_t ws_size,
                              hipStream_t stream) {
    const float* x    = (const float*)d_in[0];
    const float* Wqkv = (const float*)d_in[1];
    const float* bqkv = (const float*)d_in[2];
    const float* Wout = (const float*)d_in[3];
    const float* bout = (const float*)d_in[4];
    float* out = (float*)d_out;
    (void)in_sizes; (void)n_in; (void)out_size; (void)ws_size;

    char* ws = (char*)d_ws;
    size_t off = 0;
    auto take = [&](size_t bytes) -> void* {
        void* p = ws + off;
        off += (bytes + 255) & ~(size_t)255;
        return p;
    };
    const size_t QKV_ELEMS = (size_t)12 * 8192 * 64;  // compact seg-major total
    __bf16* WqkvT = (__bf16*)take((size_t)2304 * 768 * 2);
    __bf16* WoutT = (__bf16*)take((size_t)768 * 768 * 2);
    __bf16* Qc    = (__bf16*)take(QKV_ELEMS * 2);
    __bf16* Kc    = (__bf16*)take(QKV_ELEMS * 2);
    __bf16* Vc    = (__bf16*)take(QKV_ELEMS * 2);
    __bf16* Vt    = (__bf16*)take(QKV_ELEMS * 2);
    float*  O0    = (float*)take((size_t)2048 * 768 * 4);
    float*  O1a   = (float*)take((size_t)4096 * 768 * 4);
    float*  O1b   = (float*)take((size_t)4096 * 768 * 4);
    float*  O2    = (float*)take((size_t)2048 * 768 * 4);
    float*  L0    = (float*)take((size_t)12 * 2048 * 4);
    float*  L1a   = (float*)take((size_t)12 * 4096 * 4);
    float*  L1b   = (float*)take((size_t)12 * 4096 * 4);
    float*  L2    = (float*)take((size_t)12 * 2048 * 4);
    __bf16* attnF = Qc;  // alias: Qc dead after attn_kernel

    transpose_cvt_kernel<<<dim3(9, 96), 256, 0, stream>>>(Wqkv, WqkvT, 2304);
    transpose_cvt_kernel<<<dim3(3, 96), 256, 0, stream>>>(Wout, WoutT, 768);
    gemm_kernel<<<dim3(64, 18), 256, 0, stream>>>(x, nullptr, WqkvT, bqkv, Qc, Kc, Vc,
                                                  nullptr, 0);
    vtrans_kernel<<<1536, 256, 0, stream>>>(Vc, Vt);
    attn_kernel<<<1152, 256, 0, stream>>>(Qc, Kc, Vt, O0, O1a, O1b, O2, L0, L1a, L1b, L2);
    combine_kernel<<<3072, 256, 0, stream>>>(O0, O1a, O1b, O2, L0, L1a, L1b, L2, attnF);
    gemm_kernel<<<dim3(64, 6), 256, 0, stream>>>(nullptr, attnF, WoutT, bout, nullptr,
                                                 nullptr, nullptr, out, 1);
}